// Round 1
// baseline (2059.408 us; speedup 1.0000x reference)
//
#include <hip/hip_runtime.h>

// NucleiGNN fused forward: B=2048 molecules, one block per molecule.
// bf16 path: MFMA (v_mfma_f32_16x16x32_bf16) for all matmuls, h resident in
// C-fragment registers (transposed orientation), XOR-swizzled bf16 LDS tiles,
// 70KB LDS -> 2 blocks/CU. Weights pre-transposed into d_ws by a setup kernel.
// f32 path (and bf16 fallback if workspace too small): original VALU kernel.

#define NBATCH 2048
#define NATOM  64
#define NF     128
#define NLAYER 3
#define STR    132   // f32 row stride for 64x128 LDS tiles (legacy kernel)
#define ASTR   65    // attention row stride (legacy kernel)
#define NTH    512

__device__ __forceinline__ float bf2f(unsigned short u) {
    union { unsigned int i; float f; } v; v.i = ((unsigned int)u) << 16; return v.f;
}
__device__ __forceinline__ unsigned short f2bf(float f) {
    union { float ff; unsigned int i; } v; v.ff = f;
    unsigned int x = v.i;
    if ((x & 0x7f800000u) == 0x7f800000u) return (unsigned short)(x >> 16);
    return (unsigned short)((x + 0x7fffu + ((x >> 16) & 1u)) >> 16);
}
// fast RNE pack (values known finite inside the MFMA kernel)
__device__ __forceinline__ unsigned short f2bf_f(float f) {
    union { float ff; unsigned int i; } v; v.ff = f;
    return (unsigned short)((v.i + 0x7fffu + ((v.i >> 16) & 1u)) >> 16);
}

template<bool BF16>
__device__ __forceinline__ float ldT(const void* p, int i) {
    if constexpr (BF16) return bf2f(((const unsigned short*)p)[i]);
    else                return ((const float*)p)[i];
}
template<bool BF16>
__device__ __forceinline__ float4 ld4T(const void* p, int i) {
    if constexpr (BF16) {
        ushort4 v = *(const ushort4*)((const unsigned short*)p + i);
        return make_float4(bf2f(v.x), bf2f(v.y), bf2f(v.z), bf2f(v.w));
    } else {
        return *(const float4*)((const float*)p + i);
    }
}

// ---------------- legacy VALU kernel (f32 path + bf16 fallback) ----------------

template<bool BF16>
__device__ __forceinline__ void mm16(const float* __restrict__ src,
                                     const void* __restrict__ W, int wbase,
                                     float acc[4][4], int r0, int fq)
{
    #pragma unroll 4
    for (int kk4 = 0; kk4 < 32; ++kk4) {
        float a[4][4];
        #pragma unroll
        for (int i = 0; i < 4; ++i) {
            float4 av = *(const float4*)&src[(r0 + i) * STR + kk4 * 4];
            a[i][0] = av.x; a[i][1] = av.y; a[i][2] = av.z; a[i][3] = av.w;
        }
        #pragma unroll
        for (int kc = 0; kc < 4; ++kc) {
            float4 wv = ld4T<BF16>(W, wbase + (kk4 * 4 + kc) * NF + fq * 4);
            #pragma unroll
            for (int i = 0; i < 4; ++i) {
                acc[i][0] += a[i][kc] * wv.x;
                acc[i][1] += a[i][kc] * wv.y;
                acc[i][2] += a[i][kc] * wv.z;
                acc[i][3] += a[i][kc] * wv.w;
            }
        }
    }
}

template<bool BF16>
__device__ __forceinline__ void block_ln(const float (&h)[4][4], float* __restrict__ buf,
                                         float* __restrict__ part, float* __restrict__ part2,
                                         float* __restrict__ mu_s, float* __restrict__ rs_s,
                                         int t, int r0, int fq,
                                         void* __restrict__ outp, int obase)
{
    #pragma unroll
    for (int i = 0; i < 4; ++i)
        *(float4*)&buf[(r0 + i) * STR + fq * 4] = make_float4(h[i][0], h[i][1], h[i][2], h[i][3]);
    __syncthreads();
    {
        int r = t >> 3, q = t & 7;
        const float* p = &buf[r * STR + q * 16];
        float s = 0.f, s2 = 0.f;
        #pragma unroll
        for (int j = 0; j < 16; ++j) { float x = p[j]; s += x; s2 += x * x; }
        part[r * 8 + q] = s; part2[r * 8 + q] = s2;
    }
    __syncthreads();
    if (t < 64) {
        float s = 0.f, s2 = 0.f;
        #pragma unroll
        for (int q = 0; q < 8; ++q) { s += part[t * 8 + q]; s2 += part2[t * 8 + q]; }
        float mu = s * (1.f / 128.f);
        float var = s2 * (1.f / 128.f) - mu * mu;
        mu_s[t] = mu; rs_s[t] = rsqrtf(fmaxf(var, 0.f) + 1e-5f);
    }
    __syncthreads();
    if (outp == nullptr) {
        #pragma unroll
        for (int i = 0; i < 4; ++i) {
            float mu = mu_s[r0 + i], rs = rs_s[r0 + i];
            *(float4*)&buf[(r0 + i) * STR + fq * 4] =
                make_float4((h[i][0]-mu)*rs, (h[i][1]-mu)*rs, (h[i][2]-mu)*rs, (h[i][3]-mu)*rs);
        }
        __syncthreads();
    } else {
        #pragma unroll
        for (int i = 0; i < 4; ++i) {
            float mu = mu_s[r0 + i], rs = rs_s[r0 + i];
            int idx = obase + (r0 + i) * NF + fq * 4;
            if constexpr (BF16) {
                ushort4 o;
                o.x = f2bf((h[i][0]-mu)*rs); o.y = f2bf((h[i][1]-mu)*rs);
                o.z = f2bf((h[i][2]-mu)*rs); o.w = f2bf((h[i][3]-mu)*rs);
                *(ushort4*)((unsigned short*)outp + idx) = o;
            } else {
                *(float4*)((float*)outp + idx) =
                    make_float4((h[i][0]-mu)*rs, (h[i][1]-mu)*rs, (h[i][2]-mu)*rs, (h[i][3]-mu)*rs);
            }
        }
    }
}

template<bool BF16>
__global__ __launch_bounds__(NTH)
void gnn_fused(const void* __restrict__ coords,
               const int* __restrict__ species,
               const unsigned char* __restrict__ maskraw,
               const void* __restrict__ embed,
               const void* __restrict__ Wq,
               const void* __restrict__ Wk,
               const void* __restrict__ Wv,
               const void* __restrict__ Wo,
               const void* __restrict__ We,
               const void* __restrict__ Wf,
               const void* __restrict__ bfb,
               void* __restrict__ out)
{
    {
        const unsigned int* w = (const unsigned int*)Wq;
        bool isbf = true;
        #pragma unroll
        for (int i = 0; i < 16; ++i) {
            unsigned int e = (w[i] >> 7) & 0xFFu;
            isbf = isbf && (e >= 0x60u && e <= 0x7Eu);
        }
        if (isbf != BF16) return;
    }

    extern __shared__ float smem[];
    float* hn    = smem;
    float* qm    = hn + NATOM * STR;
    float* kb    = qm + NATOM * STR;
    float* vb    = kb + NATOM * STR;
    float* ah    = vb + NATOM * STR;
    float* cs    = ah + NATOM * ASTR;
    float* wel   = cs + NATOM * 4;
    float* mu_s  = wel + 48;
    float* rs_s  = mu_s + NATOM;
    float* part  = rs_s + NATOM;
    float* part2 = part + NATOM * 8;
    int*   lenp  = (int*)(part2 + NATOM * 8);

    const int t  = threadIdx.x;
    const int b  = blockIdx.x;
    const int fq = t & 31;
    const int rg = t >> 5;
    const int r0 = rg * 4;

    if (t < 64) {
        cs[t * 4 + 0] = ldT<BF16>(coords, (b * NATOM + t) * 3 + 0);
        cs[t * 4 + 1] = ldT<BF16>(coords, (b * NATOM + t) * 3 + 1);
        cs[t * 4 + 2] = ldT<BF16>(coords, (b * NATOM + t) * 3 + 2);
    }
    if (t >= 64 && t < 64 + 42) wel[t - 64] = ldT<BF16>(We, t - 64);
    if (t < 64) {
        unsigned int w0 = *(const unsigned int*)maskraw;
        bool f;
        if (w0 == 1u)               f = ((const int*)maskraw)[b * NATOM + t] != 0;
        else if (w0 == 0x01010101u) f = maskraw[b * NATOM + t] != 0;
        else if (w0 == 0x3F800000u) f = ((const float*)maskraw)[b * NATOM + t] != 0.f;
        else                        f = ((const unsigned short*)maskraw)[b * NATOM + t] != 0;
        unsigned long long bal = __ballot(f);
        if (t == 0) *lenp = (int)__popcll(bal);
    }

    float h[4][4];
    #pragma unroll
    for (int i = 0; i < 4; ++i) {
        int row = r0 + i;
        int sp = species[b * NATOM + row];
        float4 ev = ld4T<BF16>(embed, (sp - 1) * NF + fq * 4);
        h[i][0] = ev.x; h[i][1] = ev.y; h[i][2] = ev.z; h[i][3] = ev.w;
    }
    __syncthreads();
    const int len = *lenp;
    #pragma unroll
    for (int i = 0; i < 4; ++i)
        if (r0 + i >= len) { h[i][0] = 0.f; h[i][1] = 0.f; h[i][2] = 0.f; h[i][3] = 0.f; }

    for (int l = 0; l < NLAYER; ++l) {
        block_ln<BF16>(h, hn, part, part2, mu_s, rs_s, t, r0, fq, nullptr, 0);

        {
            float acc[4][4];
            #pragma unroll
            for (int i = 0; i < 4; ++i) { acc[i][0]=acc[i][1]=acc[i][2]=acc[i][3]=0.f; }
            mm16<BF16>(hn, Wq, l * NF * NF, acc, r0, fq);
            #pragma unroll
            for (int i = 0; i < 4; ++i)
                *(float4*)&qm[(r0 + i) * STR + fq * 4] = make_float4(acc[i][0],acc[i][1],acc[i][2],acc[i][3]);
            #pragma unroll
            for (int i = 0; i < 4; ++i) { acc[i][0]=acc[i][1]=acc[i][2]=acc[i][3]=0.f; }
            mm16<BF16>(hn, Wk, l * NF * NF, acc, r0, fq);
            #pragma unroll
            for (int i = 0; i < 4; ++i)
                *(float4*)&kb[(r0 + i) * STR + fq * 4] = make_float4(acc[i][0],acc[i][1],acc[i][2],acc[i][3]);
            #pragma unroll
            for (int i = 0; i < 4; ++i) { acc[i][0]=acc[i][1]=acc[i][2]=acc[i][3]=0.f; }
            mm16<BF16>(hn, Wv, l * NF * NF, acc, r0, fq);
            #pragma unroll
            for (int i = 0; i < 4; ++i)
                *(float4*)&vb[(r0 + i) * STR + fq * 4] = make_float4(acc[i][0],acc[i][1],acc[i][2],acc[i][3]);
        }
        __syncthreads();

        for (int hd = 0; hd < 2; ++hd) {
            const int hoff = hd * 64;
            const int n = t >> 3, mq = t & 7;
            float we_[7];
            #pragma unroll
            for (int e = 0; e < 7; ++e) we_[e] = wel[l * 14 + e * 2 + hd];
            float lg[8];
            #pragma unroll
            for (int j = 0; j < 8; ++j) lg[j] = 0.f;
            #pragma unroll
            for (int dc = 0; dc < 4; ++dc) {
                float qr[16];
                #pragma unroll
                for (int x = 0; x < 4; ++x) {
                    float4 v4 = *(const float4*)&qm[n * STR + hoff + dc * 16 + x * 4];
                    qr[x*4+0]=v4.x; qr[x*4+1]=v4.y; qr[x*4+2]=v4.z; qr[x*4+3]=v4.w;
                }
                #pragma unroll
                for (int j = 0; j < 8; ++j) {
                    const float* kp = &kb[(mq + 8 * j) * STR + hoff + dc * 16];
                    float s = 0.f;
                    #pragma unroll
                    for (int x = 0; x < 4; ++x) {
                        float4 k4 = *(const float4*)&kp[x * 4];
                        s += qr[x*4+0]*k4.x + qr[x*4+1]*k4.y + qr[x*4+2]*k4.z + qr[x*4+3]*k4.w;
                    }
                    lg[j] += s;
                }
            }
            float cnx = cs[n*4+0], cny = cs[n*4+1], cnz = cs[n*4+2];
            #pragma unroll
            for (int j = 0; j < 8; ++j) {
                int m = mq + 8 * j;
                float dx = cnx - cs[m*4+0];
                float dy = cny - cs[m*4+1];
                float dz = cnz - cs[m*4+2];
                float d = sqrtf(dx*dx + dy*dy + dz*dz + 1e-12f);
                float et = expf(-d);
                float s1 = 1.f / (1.f + 7.38905609893065f  * et);
                float s2 = 1.f / (1.f + 54.598150033144236f * et);
                float s3 = 1.f / (1.f + 403.4287934927351f  * et);
                lg[j] = lg[j] * 0.125f
                      + dx*we_[0] + dy*we_[1] + dz*we_[2] + d*we_[3]
                      + s1*we_[4] + s2*we_[5] + s3*we_[6];
            }
            float mx = -3e38f;
            #pragma unroll
            for (int j = 0; j < 8; ++j) if (mq + 8*j < len) mx = fmaxf(mx, lg[j]);
            mx = fmaxf(mx, __shfl_xor(mx, 1));
            mx = fmaxf(mx, __shfl_xor(mx, 2));
            mx = fmaxf(mx, __shfl_xor(mx, 4));
            float sm = 0.f;
            #pragma unroll
            for (int j = 0; j < 8; ++j) {
                lg[j] = (mq + 8*j < len) ? expf(lg[j] - mx) : 0.f;
                sm += lg[j];
            }
            sm += __shfl_xor(sm, 1); sm += __shfl_xor(sm, 2); sm += __shfl_xor(sm, 4);
            float inv = (n < len) ? (1.f / sm) : 0.f;
            #pragma unroll
            for (int j = 0; j < 8; ++j) ah[n * ASTR + mq + 8*j] = lg[j] * inv;
            __syncthreads();

            const int dcol = t & 63, rgm = t >> 6;
            float macc[8];
            #pragma unroll
            for (int i = 0; i < 8; ++i) macc[i] = 0.f;
            #pragma unroll 4
            for (int mc = 0; mc < 16; ++mc) {
                float v0 = vb[(mc*4+0) * STR + hoff + dcol];
                float v1 = vb[(mc*4+1) * STR + hoff + dcol];
                float v2 = vb[(mc*4+2) * STR + hoff + dcol];
                float v3 = vb[(mc*4+3) * STR + hoff + dcol];
                #pragma unroll
                for (int i = 0; i < 8; ++i) {
                    const float* ap = &ah[(rgm*8 + i) * ASTR + mc*4];
                    macc[i] += ap[0]*v0 + ap[1]*v1 + ap[2]*v2 + ap[3]*v3;
                }
            }
            #pragma unroll
            for (int i = 0; i < 8; ++i)
                qm[(rgm*8 + i) * STR + hoff + dcol] = macc[i];
            __syncthreads();
        }

        {
            float acc[4][4];
            #pragma unroll
            for (int i = 0; i < 4; ++i) { acc[i][0]=acc[i][1]=acc[i][2]=acc[i][3]=0.f; }
            mm16<BF16>(qm, Wo, l * NF * NF, acc, r0, fq);
            #pragma unroll
            for (int i = 0; i < 4; ++i) {
                h[i][0] += acc[i][0]; h[i][1] += acc[i][1];
                h[i][2] += acc[i][2]; h[i][3] += acc[i][3];
            }
        }
        block_ln<BF16>(h, hn, part, part2, mu_s, rs_s, t, r0, fq, nullptr, 0);
        {
            float acc[4][4];
            #pragma unroll
            for (int i = 0; i < 4; ++i) { acc[i][0]=acc[i][1]=acc[i][2]=acc[i][3]=0.f; }
            mm16<BF16>(hn, Wf, l * NF * NF, acc, r0, fq);
            float4 bv = ld4T<BF16>(bfb, l * NF + fq * 4);
            #pragma unroll
            for (int i = 0; i < 4; ++i) {
                h[i][0] += tanhf(acc[i][0] + bv.x);
                h[i][1] += tanhf(acc[i][1] + bv.y);
                h[i][2] += tanhf(acc[i][2] + bv.z);
                h[i][3] += tanhf(acc[i][3] + bv.w);
            }
        }
        #pragma unroll
        for (int i = 0; i < 4; ++i)
            if (r0 + i >= len) { h[i][0]=0.f; h[i][1]=0.f; h[i][2]=0.f; h[i][3]=0.f; }
        __syncthreads();
    }

    block_ln<BF16>(h, hn, part, part2, mu_s, rs_s, t, r0, fq, out, b * NATOM * NF);
}

static constexpr size_t SMEM_FLOATS =
    (size_t)NATOM * STR * 4 + (size_t)NATOM * ASTR + (size_t)NATOM * 4 + 48
    + NATOM + NATOM + (size_t)NATOM * 8 + (size_t)NATOM * 8 + 4;
static constexpr size_t SMEM_BYTES = SMEM_FLOATS * sizeof(float);

// ---------------- MFMA bf16 path ----------------

typedef __attribute__((ext_vector_type(8))) __bf16 bf16x8;
typedef __attribute__((ext_vector_type(4))) float  f32x4;

// Transpose the 15 weight matrices (Wq/Wk/Wv/Wo/Wf x 3 layers) into WT[f][k]
// bf16 in workspace. Runs (harmlessly) even when the data is f32.
__global__ __launch_bounds__(256)
void transpose_w(const void* Wq_, const void* Wk_, const void* Wv_,
                 const void* Wo_, const void* Wf_, unsigned short* __restrict__ wt)
{
    __shared__ unsigned short tile[128 * 136];
    const int m = blockIdx.x, a = m / 3, ly = m % 3, t = threadIdx.x;
    const unsigned short* src =
        (const unsigned short*)(a == 0 ? Wq_ : a == 1 ? Wk_ : a == 2 ? Wv_ : a == 3 ? Wo_ : Wf_)
        + ly * 16384;
    unsigned short* dst = wt + m * 16384;
    #pragma unroll
    for (int i = 0; i < 16; ++i) {
        int e = (i * 256 + t) * 4;
        int r = e >> 7, c0 = e & 127;
        ushort4 v = *(const ushort4*)(src + e);
        tile[(c0+0)*136 + r] = v.x; tile[(c0+1)*136 + r] = v.y;
        tile[(c0+2)*136 + r] = v.z; tile[(c0+3)*136 + r] = v.w;
    }
    __syncthreads();
    #pragma unroll
    for (int i = 0; i < 16; ++i) {
        int e = (i * 256 + t) * 4;
        int f = e >> 7, k0 = e & 127;
        ushort4 o = *(const ushort4*)&tile[f*136 + k0];
        *(ushort4*)(dst + e) = o;
    }
}

// Y^T = W^T * X^T for one 16-col f-stripe per wave, 4 n-frags.
// A-frag: WT rows (global, 16B); B-frag: X rows in swizzled bf16 LDS (16B).
__device__ __forceinline__ void mm_t(const unsigned short* __restrict__ wtp,
                                     const char* __restrict__ X,
                                     f32x4 (&acc)[4], int c, int g)
{
    bf16x8 a4[4];
    #pragma unroll
    for (int ks = 0; ks < 4; ++ks)
        a4[ks] = *(const bf16x8*)(wtp + c * NF + ks * 32 + 8 * g);
    #pragma unroll
    for (int ks = 0; ks < 4; ++ks) {
        #pragma unroll
        for (int nf = 0; nf < 4; ++nf) {
            const int row = nf * 16 + c;
            bf16x8 bfr = *(const bf16x8*)(X + row * 256 + ((ks * 64 + 16 * g) ^ ((row & 7) << 4)));
            acc[nf] = __builtin_amdgcn_mfma_f32_16x16x32_bf16(a4[ks], bfr, acc[nf], 0, 0, 0);
        }
    }
}

// Row mean/var of frag-resident h^T (lane: n = nf*16+c fixed per nf; 4 f-vals).
// Includes two __syncthreads().
__device__ __forceinline__ void ln_stats(const f32x4 (&h)[4],
                                         float* __restrict__ part, float* __restrict__ part2,
                                         float* __restrict__ mu_s, float* __restrict__ rs_s,
                                         int t, int w, int c)
{
    #pragma unroll
    for (int nf = 0; nf < 4; ++nf) {
        float s  = h[nf][0] + h[nf][1] + h[nf][2] + h[nf][3];
        float s2 = h[nf][0]*h[nf][0] + h[nf][1]*h[nf][1] + h[nf][2]*h[nf][2] + h[nf][3]*h[nf][3];
        s  += __shfl_xor(s, 16);  s  += __shfl_xor(s, 32);
        s2 += __shfl_xor(s2, 16); s2 += __shfl_xor(s2, 32);
        if ((t & 63) < 16) { const int n = nf * 16 + c; part[n*9 + w] = s; part2[n*9 + w] = s2; }
    }
    __syncthreads();
    if (t < 64) {
        float s = 0.f, s2 = 0.f;
        #pragma unroll
        for (int q = 0; q < 8; ++q) { s += part[t*9 + q]; s2 += part2[t*9 + q]; }
        float mu = s * (1.f / 128.f);
        float var = s2 * (1.f / 128.f) - mu * mu;
        mu_s[t] = mu; rs_s[t] = rsqrtf(fmaxf(var, 0.f) + 1e-5f);
    }
    __syncthreads();
}

__device__ __forceinline__ void st_rows(char* __restrict__ B, const f32x4 (&acc)[4],
                                        int c, int g, int f0)
{
    #pragma unroll
    for (int nf = 0; nf < 4; ++nf) {
        const int n = nf * 16 + c;
        ushort4 o;
        o.x = f2bf_f(acc[nf][0]); o.y = f2bf_f(acc[nf][1]);
        o.z = f2bf_f(acc[nf][2]); o.w = f2bf_f(acc[nf][3]);
        *(ushort4*)(B + n * 256 + ((2 * (f0 + 4 * g)) ^ ((n & 7) << 4))) = o;
    }
}

__device__ __forceinline__ void st_vt(char* __restrict__ VT_, const f32x4 (&acc)[4],
                                      int c, int g, int f0)
{
    #pragma unroll
    for (int nf = 0; nf < 4; ++nf) {
        #pragma unroll
        for (int r = 0; r < 4; ++r) {
            const int fr = f0 + 4 * g + r;
            *(unsigned short*)(VT_ + fr * 128 + ((2 * (nf * 16 + c)) ^ ((fr & 7) << 4)))
                = f2bf_f(acc[nf][r]);
        }
    }
}

__global__ __launch_bounds__(NTH, 4)
void gnn_mfma(const void* __restrict__ coords,
              const int*  __restrict__ species,
              const unsigned char* __restrict__ maskraw,
              const void* __restrict__ embed,
              const void* __restrict__ Wq,      // dtype-detect only
              const void* __restrict__ We,
              const void* __restrict__ bfb,
              const unsigned short* __restrict__ wt,
              void* __restrict__ out)
{
    {   // bf16 signature check: f32 data -> exit, legacy f32 kernel handles it
        const unsigned int* wdet = (const unsigned int*)Wq;
        bool isbf = true;
        #pragma unroll
        for (int i = 0; i < 16; ++i) {
            unsigned int e = (wdet[i] >> 7) & 0xFFu;
            isbf = isbf && (e >= 0x60u && e <= 0x7Eu);
        }
        if (!isbf) return;
    }

    extern __shared__ char smem2[];
    char* HN = smem2;                 // [64][128] bf16 swz : hn, then msg
    char* QB = HN + 16384;            // [64][128] bf16 swz : q, then P
    char* KB = QB + 16384;            // [64][128] bf16 swz : k
    char* VT = KB + 16384;            // [128][64] bf16 swz : v^T (f-major)
    float* cs    = (float*)(VT + 16384);   // 64*4
    float* wel   = cs + 256;               // 48
    float* mu_s  = wel + 48;               // 64
    float* rs_s  = mu_s + 64;              // 64
    float* part  = rs_s + 64;              // 64*9
    float* part2 = part + 576;             // 64*9
    int*   lenp  = (int*)(part2 + 576);

    const int t = threadIdx.x, b = blockIdx.x;
    const int w = t >> 6, la = t & 63, g = la >> 4, c = la & 15;
    const int f0 = w * 16;
    const f32x4 z4 = {0.f, 0.f, 0.f, 0.f};

    if (t < 64) {
        cs[t*4+0] = bf2f(((const unsigned short*)coords)[(b * NATOM + t) * 3 + 0]);
        cs[t*4+1] = bf2f(((const unsigned short*)coords)[(b * NATOM + t) * 3 + 1]);
        cs[t*4+2] = bf2f(((const unsigned short*)coords)[(b * NATOM + t) * 3 + 2]);
    }
    if (t >= 64 && t < 64 + 42) wel[t - 64] = bf2f(((const unsigned short*)We)[t - 64]);
    if (t < 64) {
        unsigned int w0 = *(const unsigned int*)maskraw;
        bool fm;
        if (w0 == 1u)               fm = ((const int*)maskraw)[b * NATOM + t] != 0;
        else if (w0 == 0x01010101u) fm = maskraw[b * NATOM + t] != 0;
        else if (w0 == 0x3F800000u) fm = ((const float*)maskraw)[b * NATOM + t] != 0.f;
        else                        fm = ((const unsigned short*)maskraw)[b * NATOM + t] != 0;
        unsigned long long bal = __ballot(fm);
        if (t == 0) *lenp = (int)__popcll(bal);
    }

    // h^T resident in C-frag layout: hst[nf][r] = h[n = nf*16+c][f = f0+4g+r]
    f32x4 hst[4];
    #pragma unroll
    for (int nf = 0; nf < 4; ++nf) {
        const int n = nf * 16 + c;
        const int sp = species[b * NATOM + n];
        ushort4 ev = *(const ushort4*)((const unsigned short*)embed + (sp - 1) * NF + f0 + 4 * g);
        hst[nf][0] = bf2f(ev.x); hst[nf][1] = bf2f(ev.y);
        hst[nf][2] = bf2f(ev.z); hst[nf][3] = bf2f(ev.w);
    }
    __syncthreads();
    const int len = *lenp;
    #pragma unroll
    for (int nf = 0; nf < 4; ++nf)
        if (nf * 16 + c >= len) hst[nf] = z4;

    const int hd = w >> 2;            // attention: wave -> (head, n-stripe)
    const int n0 = (w & 3) * 16;

    for (int ly = 0; ly < NLAYER; ++ly) {
        const unsigned short* wqT = wt + (0 * 3 + ly) * 16384;
        const unsigned short* wkT = wt + (1 * 3 + ly) * 16384;
        const unsigned short* wvT = wt + (2 * 3 + ly) * 16384;
        const unsigned short* woT = wt + (3 * 3 + ly) * 16384;
        const unsigned short* wfT = wt + (4 * 3 + ly) * 16384;

        // ---- LN1 -> HN (bf16, swizzled) ----
        ln_stats(hst, part, part2, mu_s, rs_s, t, w, c);
        #pragma unroll
        for (int nf = 0; nf < 4; ++nf) {
            const int n = nf * 16 + c;
            const float mu = mu_s[n], rs = rs_s[n];
            ushort4 o;
            o.x = f2bf_f((hst[nf][0]-mu)*rs); o.y = f2bf_f((hst[nf][1]-mu)*rs);
            o.z = f2bf_f((hst[nf][2]-mu)*rs); o.w = f2bf_f((hst[nf][3]-mu)*rs);
            *(ushort4*)(HN + n * 256 + ((2 * (f0 + 4 * g)) ^ ((n & 7) << 4))) = o;
        }
        __syncthreads();

        // ---- q,k,v = LN(h) @ W{q,k,v} ----
        {
            f32x4 acc[4] = {z4, z4, z4, z4};
            mm_t(wqT + f0 * NF, HN, acc, c, g);
            st_rows(QB, acc, c, g, f0);
            acc[0]=z4; acc[1]=z4; acc[2]=z4; acc[3]=z4;
            mm_t(wkT + f0 * NF, HN, acc, c, g);
            st_rows(KB, acc, c, g, f0);
            acc[0]=z4; acc[1]=z4; acc[2]=z4; acc[3]=z4;
            mm_t(wvT + f0 * NF, HN, acc, c, g);
            st_vt(VT, acc, c, g, f0);
        }
        __syncthreads();

        // ---- swapped QK^T: sacc[mf] = S^T[m][n], m = mf*16+4g+r, n = n0+c ----
        f32x4 sacc[4] = {z4, z4, z4, z4};
        #pragma unroll
        for (int ks = 0; ks < 2; ++ks) {
            const int bc = hd * 128 + ks * 64 + 16 * g;
            const int qrow = n0 + c;
            bf16x8 bq = *(const bf16x8*)(QB + qrow * 256 + (bc ^ ((qrow & 7) << 4)));
            #pragma unroll
            for (int mf = 0; mf < 4; ++mf) {
                const int krow = mf * 16 + c;
                bf16x8 ak = *(const bf16x8*)(KB + krow * 256 + (bc ^ ((krow & 7) << 4)));
                sacc[mf] = __builtin_amdgcn_mfma_f32_16x16x32_bf16(ak, bq, sacc[mf], 0, 0, 0);
            }
        }
        // edges + masked softmax over m (lanes sharing n: xor 16, 32)
        float we_[7];
        #pragma unroll
        for (int e = 0; e < 7; ++e) we_[e] = wel[ly * 14 + e * 2 + hd];
        const float cnx = cs[(n0+c)*4+0], cny = cs[(n0+c)*4+1], cnz = cs[(n0+c)*4+2];
        float mx = -1e30f;
        #pragma unroll
        for (int mf = 0; mf < 4; ++mf) {
            #pragma unroll
            for (int r = 0; r < 4; ++r) {
                const int m = mf * 16 + 4 * g + r;
                float dx = cnx - cs[m*4+0];
                float dy = cny - cs[m*4+1];
                float dz = cnz - cs[m*4+2];
                float d = sqrtf(dx*dx + dy*dy + dz*dz + 1e-12f);
                float et = expf(-d);
                float s1 = 1.f / (1.f + 7.38905609893065f   * et);
                float s2 = 1.f / (1.f + 54.598150033144236f * et);
                float s3 = 1.f / (1.f + 403.4287934927351f  * et);
                float val = sacc[mf][r] * 0.125f
                          + dx*we_[0] + dy*we_[1] + dz*we_[2] + d*we_[3]
                          + s1*we_[4] + s2*we_[5] + s3*we_[6];
                if (m >= len) val = -1e30f;
                sacc[mf][r] = val;
                mx = fmaxf(mx, val);
            }
        }
        mx = fmaxf(mx, __shfl_xor(mx, 16));
        mx = fmaxf(mx, __shfl_xor(mx, 32));
        float sm = 0.f;
        #pragma unroll
        for (int mf = 0; mf < 4; ++mf) {
            #pragma unroll
            for (int r = 0; r < 4; ++r) {
                float e = expf(sacc[mf][r] - mx);
                sacc[mf][r] = e; sm += e;
            }
        }
        sm += __shfl_xor(sm, 16);
        sm += __shfl_xor(sm, 32);
        const float inv = 1.f / sm;            // >= 1 valid entry per row always
        __syncthreads();                       // all q/k reads complete
        #pragma unroll
        for (int mf = 0; mf < 4; ++mf) {       // P[n][m] bf16 into QB
            const int prow = n0 + c;
            ushort4 o;
            o.x = f2bf_f(sacc[mf][0]*inv); o.y = f2bf_f(sacc[mf][1]*inv);
            o.z = f2bf_f(sacc[mf][2]*inv); o.w = f2bf_f(sacc[mf][3]*inv);
            *(ushort4*)(QB + prow * 256 + ((hd * 128 + mf * 32 + 8 * g) ^ ((prow & 7) << 4))) = o;
        }
        __syncthreads();

        // ---- PV: msg^T = V^T * P^T ; msg[n][f] into HN ----
        {
            const int d0 = (w & 3) * 16;
            f32x4 macc[4] = {z4, z4, z4, z4};
            #pragma unroll
            for (int ks = 0; ks < 2; ++ks) {
                const int vrow = hd * 64 + d0 + c;
                bf16x8 av = *(const bf16x8*)(VT + vrow * 128 + ((ks * 64 + 16 * g) ^ ((vrow & 7) << 4)));
                #pragma unroll
                for (int nf = 0; nf < 4; ++nf) {
                    const int prow = nf * 16 + c;
                    bf16x8 bp = *(const bf16x8*)(QB + prow * 256 +
                                 ((hd * 128 + ks * 64 + 16 * g) ^ ((prow & 7) << 4)));
                    macc[nf] = __builtin_amdgcn_mfma_f32_16x16x32_bf16(av, bp, macc[nf], 0, 0, 0);
                }
            }
            #pragma unroll
            for (int nf = 0; nf < 4; ++nf) {
                const int n = nf * 16 + c;
                ushort4 o;
                o.x = f2bf_f(macc[nf][0]); o.y = f2bf_f(macc[nf][1]);
                o.z = f2bf_f(macc[nf][2]); o.w = f2bf_f(macc[nf][3]);
                *(ushort4*)(HN + n * 256 + ((hd * 128 + (w & 3) * 32 + 8 * g) ^ ((n & 7) << 4))) = o;
            }
        }
        __syncthreads();

        // ---- h += msg @ Wo ----
        {
            f32x4 acc[4] = {z4, z4, z4, z4};
            mm_t(woT + f0 * NF, HN, acc, c, g);
            #pragma unroll
            for (int nf = 0; nf < 4; ++nf) hst[nf] += acc[nf];
        }
        // ---- LN2 -> HN (ln_stats' first barrier orders all Wo reads first) ----
        ln_stats(hst, part, part2, mu_s, rs_s, t, w, c);
        #pragma unroll
        for (int nf = 0; nf < 4; ++nf) {
            const int n = nf * 16 + c;
            const float mu = mu_s[n], rs = rs_s[n];
            ushort4 o;
            o.x = f2bf_f((hst[nf][0]-mu)*rs); o.y = f2bf_f((hst[nf][1]-mu)*rs);
            o.z = f2bf_f((hst[nf][2]-mu)*rs); o.w = f2bf_f((hst[nf][3]-mu)*rs);
            *(ushort4*)(HN + n * 256 + ((2 * (f0 + 4 * g)) ^ ((n & 7) << 4))) = o;
        }
        __syncthreads();
        // ---- h += tanh(LN2(h) @ Wf + bf) ----
        {
            f32x4 acc[4] = {z4, z4, z4, z4};
            mm_t(wfT + f0 * NF, HN, acc, c, g);
            ushort4 bv = *(const ushort4*)((const unsigned short*)bfb + ly * NF + f0 + 4 * g);
            const float b0 = bf2f(bv.x), b1 = bf2f(bv.y), b2 = bf2f(bv.z), b3 = bf2f(bv.w);
            #pragma unroll
            for (int nf = 0; nf < 4; ++nf) {
                hst[nf][0] += tanhf(acc[nf][0] + b0);
                hst[nf][1] += tanhf(acc[nf][1] + b1);
                hst[nf][2] += tanhf(acc[nf][2] + b2);
                hst[nf][3] += tanhf(acc[nf][3] + b3);
            }
        }
        #pragma unroll
        for (int nf = 0; nf < 4; ++nf)
            if (nf * 16 + c >= len) hst[nf] = z4;
        // next iteration's ln_stats barrier orders Wf reads vs HN rewrite
    }

    // ---- out = LN(h), bf16 ----
    ln_stats(hst, part, part2, mu_s, rs_s, t, w, c);
    unsigned short* op = (unsigned short*)out + (size_t)b * NATOM * NF;
    #pragma unroll
    for (int nf = 0; nf < 4; ++nf) {
        const int n = nf * 16 + c;
        const float mu = mu_s[n], rs = rs_s[n];
        ushort4 o;
        o.x = f2bf((hst[nf][0]-mu)*rs); o.y = f2bf((hst[nf][1]-mu)*rs);
        o.z = f2bf((hst[nf][2]-mu)*rs); o.w = f2bf((hst[nf][3]-mu)*rs);
        *(ushort4*)(op + n * NF + f0 + 4 * g) = o;
    }
}

static constexpr size_t SMEM2_BYTES =
    4 * 16384 + (256 + 48 + 64 + 64 + 576 + 576 + 4) * sizeof(float);
static constexpr size_t WT_BYTES = 15ull * 128 * 128 * 2;   // 491520

extern "C" void kernel_launch(void* const* d_in, const int* in_sizes, int n_in,
                              void* d_out, int out_size, void* d_ws, size_t ws_size,
                              hipStream_t stream) {
    const void*           coords  = d_in[0];
    const int*            species = (const int*)d_in[1];
    const unsigned char*  maskraw = (const unsigned char*)d_in[2];
    const void*           embed   = d_in[3];
    const void*           Wq      = d_in[4];
    const void*           Wk      = d_in[5];
    const void*           Wv      = d_in[6];
    const void*           Wo      = d_in[7];
    const void*           We      = d_in[8];
    const void*           Wf      = d_in[9];
    const void*           bfb     = d_in[10];

    (void)hipFuncSetAttribute((const void*)gnn_fused<true>,
                              hipFuncAttributeMaxDynamicSharedMemorySize,
                              (int)SMEM_BYTES);
    (void)hipFuncSetAttribute((const void*)gnn_fused<false>,
                              hipFuncAttributeMaxDynamicSharedMemorySize,
                              (int)SMEM_BYTES);

    const bool use_mfma = (d_ws != nullptr) && (ws_size >= WT_BYTES);
    if (use_mfma) {
        (void)hipFuncSetAttribute((const void*)gnn_mfma,
                                  hipFuncAttributeMaxDynamicSharedMemorySize,
                                  (int)SMEM2_BYTES);
        transpose_w<<<dim3(15), dim3(256), 0, stream>>>(
            Wq, Wk, Wv, Wo, Wf, (unsigned short*)d_ws);
        gnn_mfma<<<dim3(NBATCH), dim3(NTH), SMEM2_BYTES, stream>>>(
            coords, species, maskraw, embed, Wq, We, bfb,
            (const unsigned short*)d_ws, d_out);
        gnn_fused<false><<<dim3(NBATCH), dim3(NTH), SMEM_BYTES, stream>>>(
            coords, species, maskraw, embed, Wq, Wk, Wv, Wo, We, Wf, bfb, d_out);
    } else {
        gnn_fused<true><<<dim3(NBATCH), dim3(NTH), SMEM_BYTES, stream>>>(
            coords, species, maskraw, embed, Wq, Wk, Wv, Wo, We, Wf, bfb, d_out);
        gnn_fused<false><<<dim3(NBATCH), dim3(NTH), SMEM_BYTES, stream>>>(
            coords, species, maskraw, embed, Wq, Wk, Wv, Wo, We, Wf, bfb, d_out);
    }
}

// Round 2
// 495.441 us; speedup vs baseline: 4.1567x; 4.1567x over previous
//
#include <hip/hip_runtime.h>

// NucleiGNN fused forward: B=2048 molecules, one block (512 thr) per molecule.
// All matmuls on v_mfma_f32_16x16x32_f16 with f32 accumulation; h resident in
// C-fragment registers (transposed orientation). Inputs are f32 (detected at
// runtime from Wq's bit pattern; bf16 instantiation also provided). Weights are
// pre-transposed + f16-converted into a static __device__ array by transpose_w
// (no dependency on the harness workspace). XOR-swizzled f16 LDS tiles,
// ~70KB LDS -> 2 blocks/CU.

#define NBATCH 2048
#define NATOM  64
#define NF     128
#define NLAYER 3
#define NTH    512

typedef _Float16 f16;
typedef __attribute__((ext_vector_type(8))) _Float16 f16x8;
typedef __attribute__((ext_vector_type(4))) float    f32x4;

// WT[f][k] as f16 bits: 15 matrices (Wq,Wk,Wv,Wo,Wf) x 3 layers, 128x128 each.
__device__ __align__(16) unsigned short g_wt[15 * NF * NF];

__device__ __forceinline__ float bf2f(unsigned short u) {
    union { unsigned int i; float f; } v; v.i = ((unsigned int)u) << 16; return v.f;
}
__device__ __forceinline__ unsigned short f2bf(float f) {
    union { float ff; unsigned int i; } v; v.ff = f;
    unsigned int x = v.i;
    if ((x & 0x7f800000u) == 0x7f800000u) return (unsigned short)(x >> 16);
    return (unsigned short)((x + 0x7fffu + ((x >> 16) & 1u)) >> 16);
}
__device__ __forceinline__ unsigned short f2h(float f) {
    union { _Float16 h; unsigned short u; } v; v.h = (_Float16)f; return v.u;
}

template<bool BF16>
__device__ __forceinline__ float ldT(const void* p, int i) {
    if constexpr (BF16) return bf2f(((const unsigned short*)p)[i]);
    else                return ((const float*)p)[i];
}
template<bool BF16>
__device__ __forceinline__ float4 ld4T(const void* p, int i) {
    if constexpr (BF16) {
        ushort4 v = *(const ushort4*)((const unsigned short*)p + i);
        return make_float4(bf2f(v.x), bf2f(v.y), bf2f(v.z), bf2f(v.w));
    } else {
        return *(const float4*)((const float*)p + i);
    }
}

__device__ __forceinline__ bool detect_bf16(const void* Wq) {
    const unsigned int* w = (const unsigned int*)Wq;
    bool isbf = true;
    #pragma unroll
    for (int i = 0; i < 16; ++i) {
        unsigned int e = (w[i] >> 7) & 0xFFu;   // low-bf16 exponent if bf16-packed
        isbf = isbf && (e >= 0x60u && e <= 0x7Eu);
    }
    return isbf;
}

// ---- weight transpose + f16 convert: WT[f][k] = (f16)W[k][f] into g_wt ----
__global__ __launch_bounds__(256)
void transpose_w(const void* Wq_, const void* Wk_, const void* Wv_,
                 const void* Wo_, const void* Wf_)
{
    const bool isbf = detect_bf16(Wq_);
    __shared__ unsigned short tile[128 * 136];
    const int m = blockIdx.x, a = m / 3, ly = m % 3, t = threadIdx.x;
    const void* src = (a == 0 ? Wq_ : a == 1 ? Wk_ : a == 2 ? Wv_ : a == 3 ? Wo_ : Wf_);
    unsigned short* dst = g_wt + m * 16384;
    #pragma unroll
    for (int i = 0; i < 16; ++i) {
        int e = (i * 256 + t) * 4;          // elements e..e+3 = row r, cols c0..c0+3
        int r = e >> 7, c0 = e & 127;
        float4 v;
        if (isbf) {
            ushort4 u = *(const ushort4*)((const unsigned short*)src + ly * 16384 + e);
            v = make_float4(bf2f(u.x), bf2f(u.y), bf2f(u.z), bf2f(u.w));
        } else {
            v = *(const float4*)((const float*)src + ly * 16384 + e);
        }
        tile[(c0+0)*136 + r] = f2h(v.x); tile[(c0+1)*136 + r] = f2h(v.y);
        tile[(c0+2)*136 + r] = f2h(v.z); tile[(c0+3)*136 + r] = f2h(v.w);
    }
    __syncthreads();
    #pragma unroll
    for (int i = 0; i < 16; ++i) {
        int e = (i * 256 + t) * 4;
        int f = e >> 7, k0 = e & 127;
        *(ushort4*)(dst + e) = *(const ushort4*)&tile[f * 136 + k0];
    }
}

// Y^T = W^T * X^T for one 16-row f-stripe per wave, 4 n-frags.
// A-frag: WT rows (global, 16B); B-frag: X rows in swizzled f16 LDS (16B).
__device__ __forceinline__ void mm_t(const unsigned short* __restrict__ wtp,
                                     const char* __restrict__ X,
                                     f32x4 (&acc)[4], int c, int g)
{
    f16x8 a4[4];
    #pragma unroll
    for (int ks = 0; ks < 4; ++ks)
        a4[ks] = *(const f16x8*)(const void*)(wtp + c * NF + ks * 32 + 8 * g);
    #pragma unroll
    for (int ks = 0; ks < 4; ++ks) {
        #pragma unroll
        for (int nf = 0; nf < 4; ++nf) {
            const int row = nf * 16 + c;
            f16x8 bfr = *(const f16x8*)(X + row * 256 + ((ks * 64 + 16 * g) ^ ((row & 7) << 4)));
            acc[nf] = __builtin_amdgcn_mfma_f32_16x16x32_f16(a4[ks], bfr, acc[nf], 0, 0, 0);
        }
    }
}

// Row mean/var of frag-resident h^T (lane: n = nf*16+c; 4 f-vals each).
// Includes two __syncthreads() (first one also orders prior LDS reads).
__device__ __forceinline__ void ln_stats(const f32x4 (&h)[4],
                                         float* __restrict__ part, float* __restrict__ part2,
                                         float* __restrict__ mu_s, float* __restrict__ rs_s,
                                         int t, int w, int c)
{
    #pragma unroll
    for (int nf = 0; nf < 4; ++nf) {
        float s  = h[nf][0] + h[nf][1] + h[nf][2] + h[nf][3];
        float s2 = h[nf][0]*h[nf][0] + h[nf][1]*h[nf][1] + h[nf][2]*h[nf][2] + h[nf][3]*h[nf][3];
        s  += __shfl_xor(s, 16);  s  += __shfl_xor(s, 32);
        s2 += __shfl_xor(s2, 16); s2 += __shfl_xor(s2, 32);
        if ((t & 63) < 16) { const int n = nf * 16 + c; part[n*9 + w] = s; part2[n*9 + w] = s2; }
    }
    __syncthreads();
    if (t < 64) {
        float s = 0.f, s2 = 0.f;
        #pragma unroll
        for (int q = 0; q < 8; ++q) { s += part[t*9 + q]; s2 += part2[t*9 + q]; }
        float mu = s * (1.f / 128.f);
        float var = s2 * (1.f / 128.f) - mu * mu;
        mu_s[t] = mu; rs_s[t] = rsqrtf(fmaxf(var, 0.f) + 1e-5f);
    }
    __syncthreads();
}

__device__ __forceinline__ void st_rows(char* __restrict__ B, const f32x4 (&acc)[4],
                                        int c, int g, int f0)
{
    #pragma unroll
    for (int nf = 0; nf < 4; ++nf) {
        const int n = nf * 16 + c;
        ushort4 o = make_ushort4(f2h(acc[nf][0]), f2h(acc[nf][1]),
                                 f2h(acc[nf][2]), f2h(acc[nf][3]));
        *(ushort4*)(B + n * 256 + ((2 * (f0 + 4 * g)) ^ ((n & 7) << 4))) = o;
    }
}

__device__ __forceinline__ void st_vt(char* __restrict__ VT_, const f32x4 (&acc)[4],
                                      int c, int g, int f0)
{
    #pragma unroll
    for (int nf = 0; nf < 4; ++nf) {
        #pragma unroll
        for (int r = 0; r < 4; ++r) {
            const int fr = f0 + 4 * g + r;
            *(unsigned short*)(VT_ + fr * 128 + ((2 * (nf * 16 + c)) ^ ((fr & 7) << 4)))
                = f2h(acc[nf][r]);
        }
    }
}

template<bool BF16>
__global__ __launch_bounds__(NTH, 4)
void gnn_mfma(const void* __restrict__ coords,
              const int*  __restrict__ species,
              const unsigned char* __restrict__ maskraw,
              const void* __restrict__ embed,
              const void* __restrict__ Wq,      // dtype-detect only
              const void* __restrict__ We,
              const void* __restrict__ bfb,
              void* __restrict__ out)
{
    if (detect_bf16(Wq) != BF16) return;   // block-uniform early exit

    extern __shared__ char smem2[];
    char* HN = smem2;                 // [64][128] f16 swz : hn, then msg
    char* QB = HN + 16384;            // [64][128] f16 swz : q, then P
    char* KB = QB + 16384;            // [64][128] f16 swz : k
    char* VT = KB + 16384;            // [128][64] f16 swz : v^T (f-major)
    float* cs    = (float*)(VT + 16384);   // 64*4
    float* wel   = cs + 256;               // 48
    float* mu_s  = wel + 48;               // 64
    float* rs_s  = mu_s + 64;              // 64
    float* part  = rs_s + 64;              // 64*9
    float* part2 = part + 576;             // 64*9
    int*   lenp  = (int*)(part2 + 576);

    const int t = threadIdx.x, b = blockIdx.x;
    const int w = t >> 6, la = t & 63, g = la >> 4, c = la & 15;
    const int f0 = w * 16;
    const f32x4 z4 = {0.f, 0.f, 0.f, 0.f};

    if (t < 64) {
        cs[t*4+0] = ldT<BF16>(coords, (b * NATOM + t) * 3 + 0);
        cs[t*4+1] = ldT<BF16>(coords, (b * NATOM + t) * 3 + 1);
        cs[t*4+2] = ldT<BF16>(coords, (b * NATOM + t) * 3 + 2);
    }
    if (t >= 64 && t < 64 + 42) wel[t - 64] = ldT<BF16>(We, t - 64);
    if (t < 64) {
        unsigned int w0 = *(const unsigned int*)maskraw;
        bool fm;
        if (w0 == 1u)               fm = ((const int*)maskraw)[b * NATOM + t] != 0;
        else if (w0 == 0x01010101u) fm = maskraw[b * NATOM + t] != 0;
        else if (w0 == 0x3F800000u) fm = ((const float*)maskraw)[b * NATOM + t] != 0.f;
        else                        fm = ((const unsigned short*)maskraw)[b * NATOM + t] != 0;
        unsigned long long bal = __ballot(fm);
        if (t == 0) *lenp = (int)__popcll(bal);
    }

    // h^T resident in C-frag layout: hst[nf][r] = h[n = nf*16+c][f = f0+4g+r]
    f32x4 hst[4];
    #pragma unroll
    for (int nf = 0; nf < 4; ++nf) {
        const int n = nf * 16 + c;
        const int sp = species[b * NATOM + n];
        float4 ev = ld4T<BF16>(embed, (sp - 1) * NF + f0 + 4 * g);
        hst[nf][0] = ev.x; hst[nf][1] = ev.y; hst[nf][2] = ev.z; hst[nf][3] = ev.w;
    }
    __syncthreads();
    const int len = *lenp;
    #pragma unroll
    for (int nf = 0; nf < 4; ++nf)
        if (nf * 16 + c >= len) hst[nf] = z4;

    const int hd = w >> 2;            // attention: wave -> (head, n-stripe)
    const int n0 = (w & 3) * 16;

    for (int ly = 0; ly < NLAYER; ++ly) {
        const unsigned short* wqT = g_wt + (0 * 3 + ly) * 16384;
        const unsigned short* wkT = g_wt + (1 * 3 + ly) * 16384;
        const unsigned short* wvT = g_wt + (2 * 3 + ly) * 16384;
        const unsigned short* woT = g_wt + (3 * 3 + ly) * 16384;
        const unsigned short* wfT = g_wt + (4 * 3 + ly) * 16384;

        // ---- LN1 -> HN (f16, swizzled) ----
        ln_stats(hst, part, part2, mu_s, rs_s, t, w, c);
        #pragma unroll
        for (int nf = 0; nf < 4; ++nf) {
            const int n = nf * 16 + c;
            const float mu = mu_s[n], rs = rs_s[n];
            ushort4 o = make_ushort4(f2h((hst[nf][0]-mu)*rs), f2h((hst[nf][1]-mu)*rs),
                                     f2h((hst[nf][2]-mu)*rs), f2h((hst[nf][3]-mu)*rs));
            *(ushort4*)(HN + n * 256 + ((2 * (f0 + 4 * g)) ^ ((n & 7) << 4))) = o;
        }
        __syncthreads();

        // ---- q,k,v = LN(h) @ W{q,k,v} ----
        {
            f32x4 acc[4] = {z4, z4, z4, z4};
            mm_t(wqT + f0 * NF, HN, acc, c, g);
            st_rows(QB, acc, c, g, f0);
            acc[0]=z4; acc[1]=z4; acc[2]=z4; acc[3]=z4;
            mm_t(wkT + f0 * NF, HN, acc, c, g);
            st_rows(KB, acc, c, g, f0);
            acc[0]=z4; acc[1]=z4; acc[2]=z4; acc[3]=z4;
            mm_t(wvT + f0 * NF, HN, acc, c, g);
            st_vt(VT, acc, c, g, f0);
        }
        __syncthreads();

        // ---- swapped QK^T: sacc[mf] = S^T[m][n], m = mf*16+4g+r, n = n0+c ----
        f32x4 sacc[4] = {z4, z4, z4, z4};
        #pragma unroll
        for (int ks = 0; ks < 2; ++ks) {
            const int bc = hd * 128 + ks * 64 + 16 * g;
            const int qrow = n0 + c;
            f16x8 bq = *(const f16x8*)(QB + qrow * 256 + (bc ^ ((qrow & 7) << 4)));
            #pragma unroll
            for (int mf = 0; mf < 4; ++mf) {
                const int krow = mf * 16 + c;
                f16x8 ak = *(const f16x8*)(KB + krow * 256 + (bc ^ ((krow & 7) << 4)));
                sacc[mf] = __builtin_amdgcn_mfma_f32_16x16x32_f16(ak, bq, sacc[mf], 0, 0, 0);
            }
        }
        // edges + masked softmax over m (lanes sharing n: xor 16, 32)
        float we_[7];
        #pragma unroll
        for (int e = 0; e < 7; ++e) we_[e] = wel[ly * 14 + e * 2 + hd];
        const float cnx = cs[(n0+c)*4+0], cny = cs[(n0+c)*4+1], cnz = cs[(n0+c)*4+2];
        float mx = -1e30f;
        #pragma unroll
        for (int mf = 0; mf < 4; ++mf) {
            #pragma unroll
            for (int r = 0; r < 4; ++r) {
                const int m = mf * 16 + 4 * g + r;
                float dx = cnx - cs[m*4+0];
                float dy = cny - cs[m*4+1];
                float dz = cnz - cs[m*4+2];
                float d = sqrtf(dx*dx + dy*dy + dz*dz + 1e-12f);
                float et = expf(-d);
                float s1 = 1.f / (1.f + 7.38905609893065f   * et);  // sigmoid(d-2)
                float s2 = 1.f / (1.f + 54.598150033144236f * et);  // sigmoid(d-4)
                float s3 = 1.f / (1.f + 403.4287934927351f  * et);  // sigmoid(d-6)
                float val = sacc[mf][r] * 0.125f
                          + dx*we_[0] + dy*we_[1] + dz*we_[2] + d*we_[3]
                          + s1*we_[4] + s2*we_[5] + s3*we_[6];
                if (m >= len) val = -1e30f;
                sacc[mf][r] = val;
                mx = fmaxf(mx, val);
            }
        }
        mx = fmaxf(mx, __shfl_xor(mx, 16));
        mx = fmaxf(mx, __shfl_xor(mx, 32));
        float sm = 0.f;
        #pragma unroll
        for (int mf = 0; mf < 4; ++mf) {
            #pragma unroll
            for (int r = 0; r < 4; ++r) {
                float e = expf(sacc[mf][r] - mx);
                sacc[mf][r] = e; sm += e;
            }
        }
        sm += __shfl_xor(sm, 16);
        sm += __shfl_xor(sm, 32);
        const float inv = 1.f / sm;            // >= 1 valid entry per row always
        __syncthreads();                       // all q/k reads complete
        #pragma unroll
        for (int mf = 0; mf < 4; ++mf) {       // P[n][m] f16 into QB
            const int prow = n0 + c;
            ushort4 o = make_ushort4(f2h(sacc[mf][0]*inv), f2h(sacc[mf][1]*inv),
                                     f2h(sacc[mf][2]*inv), f2h(sacc[mf][3]*inv));
            *(ushort4*)(QB + prow * 256 + ((hd * 128 + mf * 32 + 8 * g) ^ ((prow & 7) << 4))) = o;
        }
        __syncthreads();

        // ---- PV: msg^T = V^T * P^T ; msg[n][f] into HN ----
        {
            const int d0 = (w & 3) * 16;
            f32x4 macc[4] = {z4, z4, z4, z4};
            #pragma unroll
            for (int ks = 0; ks < 2; ++ks) {
                const int vrow = hd * 64 + d0 + c;
                f16x8 av = *(const f16x8*)(VT + vrow * 128 + ((ks * 64 + 16 * g) ^ ((vrow & 7) << 4)));
                #pragma unroll
                for (int nf = 0; nf < 4; ++nf) {
                    const int prow = nf * 16 + c;
                    f16x8 bp = *(const f16x8*)(QB + prow * 256 +
                                 ((hd * 128 + ks * 64 + 16 * g) ^ ((prow & 7) << 4)));
                    macc[nf] = __builtin_amdgcn_mfma_f32_16x16x32_f16(av, bp, macc[nf], 0, 0, 0);
                }
            }
            #pragma unroll
            for (int nf = 0; nf < 4; ++nf) {
                const int n = nf * 16 + c;
                ushort4 o = make_ushort4(f2h(macc[nf][0]), f2h(macc[nf][1]),
                                         f2h(macc[nf][2]), f2h(macc[nf][3]));
                *(ushort4*)(HN + n * 256 + ((hd * 128 + (w & 3) * 32 + 8 * g) ^ ((n & 7) << 4))) = o;
            }
        }
        __syncthreads();

        // ---- h += msg @ Wo ----
        {
            f32x4 acc[4] = {z4, z4, z4, z4};
            mm_t(woT + f0 * NF, HN, acc, c, g);
            #pragma unroll
            for (int nf = 0; nf < 4; ++nf) hst[nf] += acc[nf];
        }
        // ---- LN2 -> HN (ln_stats' first barrier orders all Wo reads first) ----
        ln_stats(hst, part, part2, mu_s, rs_s, t, w, c);
        #pragma unroll
        for (int nf = 0; nf < 4; ++nf) {
            const int n = nf * 16 + c;
            const float mu = mu_s[n], rs = rs_s[n];
            ushort4 o = make_ushort4(f2h((hst[nf][0]-mu)*rs), f2h((hst[nf][1]-mu)*rs),
                                     f2h((hst[nf][2]-mu)*rs), f2h((hst[nf][3]-mu)*rs));
            *(ushort4*)(HN + n * 256 + ((2 * (f0 + 4 * g)) ^ ((n & 7) << 4))) = o;
        }
        __syncthreads();
        // ---- h += tanh(LN2(h) @ Wf + bf) ----
        {
            f32x4 acc[4] = {z4, z4, z4, z4};
            mm_t(wfT + f0 * NF, HN, acc, c, g);
            float4 bv = ld4T<BF16>(bfb, ly * NF + f0 + 4 * g);
            #pragma unroll
            for (int nf = 0; nf < 4; ++nf) {
                hst[nf][0] += tanhf(acc[nf][0] + bv.x);
                hst[nf][1] += tanhf(acc[nf][1] + bv.y);
                hst[nf][2] += tanhf(acc[nf][2] + bv.z);
                hst[nf][3] += tanhf(acc[nf][3] + bv.w);
            }
        }
        #pragma unroll
        for (int nf = 0; nf < 4; ++nf)
            if (nf * 16 + c >= len) hst[nf] = z4;
        // next iteration's ln_stats barrier orders Wf reads vs HN rewrite
    }

    // ---- out = LN(h), in the input dtype ----
    ln_stats(hst, part, part2, mu_s, rs_s, t, w, c);
    #pragma unroll
    for (int nf = 0; nf < 4; ++nf) {
        const int n = nf * 16 + c;
        const float mu = mu_s[n], rs = rs_s[n];
        const int idx = (b * NATOM + n) * NF + f0 + 4 * g;
        if constexpr (BF16) {
            ushort4 o = make_ushort4(f2bf((hst[nf][0]-mu)*rs), f2bf((hst[nf][1]-mu)*rs),
                                     f2bf((hst[nf][2]-mu)*rs), f2bf((hst[nf][3]-mu)*rs));
            *(ushort4*)((unsigned short*)out + idx) = o;
        } else {
            *(float4*)((float*)out + idx) =
                make_float4((hst[nf][0]-mu)*rs, (hst[nf][1]-mu)*rs,
                            (hst[nf][2]-mu)*rs, (hst[nf][3]-mu)*rs);
        }
    }
}

static constexpr size_t SMEM2_BYTES =
    4 * 16384 + (256 + 48 + 64 + 64 + 576 + 576 + 4) * sizeof(float);   // 71888

extern "C" void kernel_launch(void* const* d_in, const int* in_sizes, int n_in,
                              void* d_out, int out_size, void* d_ws, size_t ws_size,
                              hipStream_t stream) {
    const void*           coords  = d_in[0];
    const int*            species = (const int*)d_in[1];
    const unsigned char*  maskraw = (const unsigned char*)d_in[2];
    const void*           embed   = d_in[3];
    const void*           Wq      = d_in[4];
    const void*           Wk      = d_in[5];
    const void*           Wv      = d_in[6];
    const void*           Wo      = d_in[7];
    const void*           We      = d_in[8];
    const void*           Wf      = d_in[9];
    const void*           bfb     = d_in[10];
    (void)d_ws; (void)ws_size; (void)in_sizes; (void)n_in; (void)out_size;

    (void)hipFuncSetAttribute((const void*)gnn_mfma<false>,
                              hipFuncAttributeMaxDynamicSharedMemorySize,
                              (int)SMEM2_BYTES);
    (void)hipFuncSetAttribute((const void*)gnn_mfma<true>,
                              hipFuncAttributeMaxDynamicSharedMemorySize,
                              (int)SMEM2_BYTES);

    transpose_w<<<dim3(15), dim3(256), 0, stream>>>(Wq, Wk, Wv, Wo, Wf);
    gnn_mfma<false><<<dim3(NBATCH), dim3(NTH), SMEM2_BYTES, stream>>>(
        coords, species, maskraw, embed, Wq, We, bfb, d_out);
    gnn_mfma<true><<<dim3(NBATCH), dim3(NTH), SMEM2_BYTES, stream>>>(
        coords, species, maskraw, embed, Wq, We, bfb, d_out);
}